// Round 1
// baseline (18500.000 us; speedup 1.0000x reference)
//
#include <hip/hip_runtime.h>
#include <hip/hip_bf16.h>

typedef short s16x8 __attribute__((ext_vector_type(8)));
typedef float f32x4 __attribute__((ext_vector_type(4)));

__device__ __forceinline__ float bf2f(short s) {
  union { unsigned int u; float f; } c; c.u = ((unsigned int)(unsigned short)s) << 16; return c.f;
}
__device__ __forceinline__ short f2bf(float f) {
  union { float f; unsigned int u; } c; c.f = f;
  unsigned int r = (c.u + 0x7fffu + ((c.u >> 16) & 1u)) >> 16;
  return (short)(unsigned short)r;
}
__device__ __forceinline__ float sigm(float x) { return 1.0f / (1.0f + __expf(-x)); }

__device__ __forceinline__ void gload_lds16(const short* g, short* l) {
  __builtin_amdgcn_global_load_lds((const __attribute__((address_space(1))) void*)g,
                                   (__attribute__((address_space(3))) void*)l, 16, 0, 0);
}

// ---------------- prep: f32 -> bf16 conversions + h init ----------------
__global__ void prep(const float* __restrict__ x,
                     const float* __restrict__ Wfz, const float* __restrict__ Wfr, const float* __restrict__ Wfh,
                     const float* __restrict__ Wuz, const float* __restrict__ Wur, const float* __restrict__ Wuh,
                     const float* __restrict__ h0,
                     short* __restrict__ xb, short* __restrict__ Wf, short* __restrict__ Wzr,
                     short* __restrict__ Wh, float* __restrict__ hf, short* __restrict__ hb)
{
  const long NX = 33554432L;      // 64*512*1024
  const long NW = 1048576L;       // 1024*1024
  const long TOT = NX + 3*NW + 2*NW + NW + 65536L;
  long stride = (long)gridDim.x * blockDim.x;
  for (long p = (long)blockIdx.x * blockDim.x + threadIdx.x; p < TOT; p += stride) {
    if (p < NX) { xb[p] = f2bf(x[p]); }
    else if (p < NX + 3*NW) {
      long q = p - NX;
      float v = q < NW ? Wfz[q] : (q < 2*NW ? Wfr[q-NW] : Wfh[q-2*NW]);
      Wf[q] = f2bf(v);
    } else if (p < NX + 5*NW) {
      long q = p - NX - 3*NW;
      float v = q < NW ? Wuz[q] : Wur[q-NW];
      Wzr[q] = f2bf(v);
    } else if (p < NX + 6*NW) {
      long q = p - NX - 5*NW;
      Wh[q] = f2bf(Wuh[q]);
    } else {
      long q = p - NX - 6*NW;
      float v = h0[q];
      hf[q] = v; hb[q] = f2bf(v);
    }
  }
}

// ---------------- input GEMM: X[t][b][n] = bf16( x@WfT + bias ) ----------------
// C[m,n] = sum_k A[m,k]*Bw[n,k];  A=[32768,1024] bf16, Bw=[3072,1024] bf16
__global__ __launch_bounds__(256) void gemm_x(const short* __restrict__ A, const short* __restrict__ Bw,
    const float* __restrict__ bfz, const float* __restrict__ bfr, const float* __restrict__ bfh,
    short* __restrict__ X)
{
  constexpr int M = 32768, K = 1024;
  constexpr int BM = 128, BN = 128, BK = 32;
  __shared__ __align__(16) short As[BM*BK];
  __shared__ __align__(16) short Bs[BN*BK];
  int tid = threadIdx.x, lane = tid & 63, wid = tid >> 6;
  int bm = blockIdx.x % (M/BM), bn = blockIdx.x / (M/BM);
  int wm = wid >> 1, wn = wid & 1;

  f32x4 acc[4][4];
  for (int i = 0; i < 4; ++i) for (int j = 0; j < 4; ++j) acc[i][j] = f32x4{0.f,0.f,0.f,0.f};

  // staging coords: linear id g = instr*256 + tid ; row = g>>2 ; kcol = (g&3)*8
  int r0 = tid >> 2,        kc0 = (tid & 3) * 8;
  int r1 = (256+tid) >> 2,  kc1 = ((256+tid) & 3) * 8;
  const short* a0 = A  + (size_t)(bm*BM + r0)*K + kc0;
  const short* a1 = A  + (size_t)(bm*BM + r1)*K + kc1;
  const short* b0 = Bw + (size_t)(bn*BN + r0)*K + kc0;
  const short* b1 = Bw + (size_t)(bn*BN + r1)*K + kc1;

  const short* abase = As + (wm*64 + (lane&15))*BK + (lane>>4)*8;
  const short* bbase = Bs + (wn*64 + (lane&15))*BK + (lane>>4)*8;

  for (int k0 = 0; k0 < K; k0 += BK) {
    __syncthreads();
    gload_lds16(a0 + k0, As + wid*512);
    gload_lds16(a1 + k0, As + 2048 + wid*512);
    gload_lds16(b0 + k0, Bs + wid*512);
    gload_lds16(b1 + k0, Bs + 2048 + wid*512);
    __syncthreads();
    s16x8 af[4], bff[4];
    for (int f = 0; f < 4; ++f) {
      af[f]  = *(const s16x8*)(abase + f*16*BK);
      bff[f] = *(const s16x8*)(bbase + f*16*BK);
    }
    for (int i = 0; i < 4; ++i)
      for (int j = 0; j < 4; ++j)
        acc[i][j] = __builtin_amdgcn_mfma_f32_16x16x32_bf16(af[i], bff[j], acc[i][j], 0, 0, 0);
  }

  int col = lane & 15, rb = (lane >> 4) * 4;
  for (int fi = 0; fi < 4; ++fi) for (int fj = 0; fj < 4; ++fj) {
    int n = bn*BN + wn*64 + fj*16 + col;
    float bias = n < 1024 ? bfz[n] : (n < 2048 ? bfr[n-1024] : bfh[n-2048]);
    f32x4 c = acc[fi][fj];
    for (int i = 0; i < 4; ++i) {
      int m = bm*BM + wm*64 + fi*16 + rb + i;
      int bb = m >> 9, tt = m & 511;
      X[((size_t)tt*64 + bb)*3072 + n] = f2bf(c[i] + bias);
    }
  }
}

// ---------------- global barrier ----------------
__device__ __forceinline__ void gbar(int* cnt, int* gen, int expect) {
  __syncthreads();
  if (threadIdx.x == 0) {
    __threadfence();   // release: flush this XCD's stores to the coherent point
    int a = __hip_atomic_fetch_add(cnt, 1, __ATOMIC_RELAXED, __HIP_MEMORY_SCOPE_AGENT);
    if (a == 63) {
      __hip_atomic_store(cnt, 0, __ATOMIC_RELAXED, __HIP_MEMORY_SCOPE_AGENT);
      __hip_atomic_store(gen, expect, __ATOMIC_RELEASE, __HIP_MEMORY_SCOPE_AGENT);
    } else {
      while (__hip_atomic_load(gen, __ATOMIC_ACQUIRE, __HIP_MEMORY_SCOPE_AGENT) < expect)
        __builtin_amdgcn_s_sleep(2);
    }
    __threadfence();   // acquire: invalidate L1/L2 so fresh data is re-fetched
  }
  __syncthreads();
}

// ---------------- persistent recurrence: 64 wgs x 256 thr ----------------
__global__ __launch_bounds__(256) void recur(
  const short* __restrict__ X,    // [512][64][3072] bf16 (bias included)
  const short* __restrict__ Wzr,  // [2048][1024] bf16 (Wuz rows 0..1023, Wur 1024..2047)
  const short* __restrict__ Wh,   // [1024][1024] bf16
  const float* __restrict__ buz, const float* __restrict__ bur, const float* __restrict__ buh,
  float* hf, short* hb,           // [2][64][1024]
  short* rh, float* zb,           // [64][1024]
  float* y, float* hlast, int* bar)
{
  int wg = blockIdx.x, tid = threadIdx.x, lane = tid & 63, wid = tid >> 6;
  int col = lane & 15, rb = (lane >> 4) * 4, kfo = (lane >> 4) * 8;
  int arow = wid*16 + (lane & 15);
  int expect = 0;

  for (int t = 0; t < 512; ++t) {
    int cur = t & 1, nxt = cur ^ 1;
    const short* hbc = hb + cur*65536;
    const float* hfc = hf + cur*65536;

    { // phase 1: C[64 x 32] over zr columns c0..c0+31
      int c0 = wg * 32;
      f32x4 ac0 = {0.f,0.f,0.f,0.f}, ac1 = {0.f,0.f,0.f,0.f};
      const short* ap  = hbc + arow*1024 + kfo;
      const short* bp0 = Wzr + (size_t)(c0 + col)*1024 + kfo;
      const short* bp1 = bp0 + (size_t)16*1024;
      #pragma unroll 8
      for (int k0 = 0; k0 < 1024; k0 += 32) {
        s16x8 av = *(const s16x8*)(ap  + k0);
        s16x8 b0 = *(const s16x8*)(bp0 + k0);
        s16x8 b1 = *(const s16x8*)(bp1 + k0);
        ac0 = __builtin_amdgcn_mfma_f32_16x16x32_bf16(av, b0, ac0, 0,0,0);
        ac1 = __builtin_amdgcn_mfma_f32_16x16x32_bf16(av, b1, ac1, 0,0,0);
      }
      for (int fn = 0; fn < 2; ++fn) {
        f32x4 c = fn ? ac1 : ac0;
        int cc = c0 + fn*16 + col;
        if (cc < 1024) {          // z columns
          int j = cc; float bias = buz[j];
          for (int i = 0; i < 4; ++i) {
            int b = wid*16 + rb + i;
            float xv = bf2f(X[((size_t)t*64 + b)*3072 + j]);
            zb[b*1024 + j] = sigm(xv + c[i] + bias);
          }
        } else {                  // r columns -> store rh = r * h
          int j = cc - 1024; float bias = bur[j];
          for (int i = 0; i < 4; ++i) {
            int b = wid*16 + rb + i;
            float xv = bf2f(X[((size_t)t*64 + b)*3072 + 1024 + j]);
            float r = sigm(xv + c[i] + bias);
            rh[b*1024 + j] = f2bf(r * hfc[b*1024 + j]);
          }
        }
      }
    }
    gbar(bar, bar+1, ++expect);

    { // phase 2: C[64 x 16] = rh @ Wh.T slice, combine, write y/h
      int j0 = wg * 16;
      f32x4 ac = {0.f,0.f,0.f,0.f};
      const short* ap = rh + arow*1024 + kfo;
      const short* bp = Wh + (size_t)(j0 + col)*1024 + kfo;
      #pragma unroll 8
      for (int k0 = 0; k0 < 1024; k0 += 32) {
        s16x8 av = *(const s16x8*)(ap + k0);
        s16x8 bv = *(const s16x8*)(bp + k0);
        ac = __builtin_amdgcn_mfma_f32_16x16x32_bf16(av, bv, ac, 0,0,0);
      }
      float* hfn = hf + nxt*65536;
      short* hbn = hb + nxt*65536;
      int j = j0 + col;
      float bias = buh[j];
      for (int i = 0; i < 4; ++i) {
        int b = wid*16 + rb + i;
        float xv = bf2f(X[((size_t)t*64 + b)*3072 + 2048 + j]);
        float s  = xv + ac[i] + bias;
        float hh = s * sigm(s);            // silu
        float z  = zb[b*1024 + j];
        float hp = hfc[b*1024 + j];
        float hn = (1.0f - z)*hp + z*hh;
        hfn[b*1024 + j] = hn;
        hbn[b*1024 + j] = f2bf(hn);
        y[((size_t)b*512 + t)*1024 + j] = hn;
        if (t == 511) hlast[b*1024 + j] = hn;
      }
    }
    gbar(bar, bar+1, ++expect);
  }
}

extern "C" void kernel_launch(void* const* d_in, const int* in_sizes, int n_in,
                              void* d_out, int out_size, void* d_ws, size_t ws_size,
                              hipStream_t stream) {
  const float* x   = (const float*)d_in[0];
  const float* h0  = (const float*)d_in[1];
  const float* Wfz = (const float*)d_in[2];
  const float* bfz = (const float*)d_in[3];
  const float* Wfr = (const float*)d_in[4];
  const float* bfr = (const float*)d_in[5];
  const float* Wfh = (const float*)d_in[6];
  const float* bfh = (const float*)d_in[7];
  const float* Wuz = (const float*)d_in[8];
  const float* buz = (const float*)d_in[9];
  const float* Wur = (const float*)d_in[10];
  const float* bur = (const float*)d_in[11];
  const float* Wuh = (const float*)d_in[12];
  const float* buh = (const float*)d_in[13];

  char* ws = (char*)d_ws;
  short* Xb  = (short*)(ws);                  // 201326592 B  [512][64][3072] bf16
  short* xb  = (short*)(ws + 201326592);      //  67108864 B  x bf16
  short* Wf  = (short*)(ws + 268435456);      //   6291456 B  [3072][1024]
  short* Wzr = (short*)(ws + 274726912);      //   4194304 B  [2048][1024]
  short* Wh  = (short*)(ws + 278921216);      //   2097152 B  [1024][1024]
  float* hf  = (float*)(ws + 281018368);      //    524288 B  [2][64][1024] f32
  short* hb  = (short*)(ws + 281542656);      //    262144 B  [2][64][1024] bf16
  short* rh  = (short*)(ws + 281804800);      //    131072 B  [64][1024] bf16
  float* zb  = (float*)(ws + 281935872);      //    262144 B  [64][1024] f32
  int*   bar = (int*)(ws + 282198016);        //    barrier cnt/gen

  float* y = (float*)d_out;
  float* hlast = y + 33554432;                // 64*512*1024

  hipMemsetAsync(bar, 0, 64, stream);
  prep<<<2048, 256, 0, stream>>>(x, Wfz, Wfr, Wfh, Wuz, Wur, Wuh, h0, xb, Wf, Wzr, Wh, hf, hb);
  gemm_x<<<6144, 256, 0, stream>>>(xb, Wf, bfz, bfr, bfh, Xb);
  recur<<<64, 256, 0, stream>>>(Xb, Wzr, Wh, buz, bur, buh, hf, hb, rh, zb, y, hlast, bar);
}

// Round 2
// 16056.134 us; speedup vs baseline: 1.1522x; 1.1522x over previous
//
#include <hip/hip_runtime.h>
#include <hip/hip_bf16.h>

typedef short s16x8 __attribute__((ext_vector_type(8)));
typedef float f32x4 __attribute__((ext_vector_type(4)));

__device__ __forceinline__ float bf2f(short s) {
  union { unsigned int u; float f; } c; c.u = ((unsigned int)(unsigned short)s) << 16; return c.f;
}
__device__ __forceinline__ short f2bf(float f) {
  union { float f; unsigned int u; } c; c.f = f;
  unsigned int r = (c.u + 0x7fffu + ((c.u >> 16) & 1u)) >> 16;
  return (short)(unsigned short)r;
}
__device__ __forceinline__ float sigm(float x) { return 1.0f / (1.0f + __expf(-x)); }

__device__ __forceinline__ void gload_lds16(const short* g, short* l) {
  __builtin_amdgcn_global_load_lds((const __attribute__((address_space(1))) void*)g,
                                   (__attribute__((address_space(3))) void*)l, 16, 0, 0);
}

// coherent (LLC-resolving) 16B load as two 8B agent-scope atomic loads
__device__ __forceinline__ s16x8 loadA16(const short* p) {
  unsigned long long v0 = __hip_atomic_load((const unsigned long long*)p,
                                            __ATOMIC_RELAXED, __HIP_MEMORY_SCOPE_AGENT);
  unsigned long long v1 = __hip_atomic_load((const unsigned long long*)(p + 4),
                                            __ATOMIC_RELAXED, __HIP_MEMORY_SCOPE_AGENT);
  union { unsigned long long u[2]; s16x8 s; } c; c.u[0] = v0; c.u[1] = v1; return c.s;
}

// ---------------- prep: f32 -> bf16 conversions + h init ----------------
__global__ void prep(const float* __restrict__ x,
                     const float* __restrict__ Wfz, const float* __restrict__ Wfr, const float* __restrict__ Wfh,
                     const float* __restrict__ Wuz, const float* __restrict__ Wur, const float* __restrict__ Wuh,
                     const float* __restrict__ h0,
                     short* __restrict__ xb, short* __restrict__ Wf, short* __restrict__ Wzr,
                     short* __restrict__ Wh, short* __restrict__ hb)
{
  const long NX = 33554432L;      // 64*512*1024
  const long NW = 1048576L;       // 1024*1024
  const long TOT = NX + 6*NW + 65536L;
  long stride = (long)gridDim.x * blockDim.x;
  for (long p = (long)blockIdx.x * blockDim.x + threadIdx.x; p < TOT; p += stride) {
    if (p < NX) { xb[p] = f2bf(x[p]); }
    else if (p < NX + 3*NW) {
      long q = p - NX;
      float v = q < NW ? Wfz[q] : (q < 2*NW ? Wfr[q-NW] : Wfh[q-2*NW]);
      Wf[q] = f2bf(v);
    } else if (p < NX + 5*NW) {
      long q = p - NX - 3*NW;
      float v = q < NW ? Wuz[q] : Wur[q-NW];
      Wzr[q] = f2bf(v);
    } else if (p < NX + 6*NW) {
      long q = p - NX - 5*NW;
      Wh[q] = f2bf(Wuh[q]);
    } else {
      long q = p - NX - 6*NW;
      hb[q] = f2bf(h0[q]);
    }
  }
}

// ---------------- input GEMM: X[t][b][n] = bf16( x@WfT + bias ) ----------------
__global__ __launch_bounds__(256) void gemm_x(const short* __restrict__ A, const short* __restrict__ Bw,
    const float* __restrict__ bfz, const float* __restrict__ bfr, const float* __restrict__ bfh,
    short* __restrict__ X)
{
  constexpr int M = 32768, K = 1024;
  constexpr int BM = 128, BN = 128, BK = 32;
  __shared__ __align__(16) short As[BM*BK];
  __shared__ __align__(16) short Bs[BN*BK];
  int tid = threadIdx.x, lane = tid & 63, wid = tid >> 6;
  int bm = blockIdx.x % (M/BM), bn = blockIdx.x / (M/BM);
  int wm = wid >> 1, wn = wid & 1;

  f32x4 acc[4][4];
  for (int i = 0; i < 4; ++i) for (int j = 0; j < 4; ++j) acc[i][j] = f32x4{0.f,0.f,0.f,0.f};

  int r0 = tid >> 2,        kc0 = (tid & 3) * 8;
  int r1 = (256+tid) >> 2,  kc1 = ((256+tid) & 3) * 8;
  const short* a0 = A  + (size_t)(bm*BM + r0)*K + kc0;
  const short* a1 = A  + (size_t)(bm*BM + r1)*K + kc1;
  const short* b0 = Bw + (size_t)(bn*BN + r0)*K + kc0;
  const short* b1 = Bw + (size_t)(bn*BN + r1)*K + kc1;

  const short* abase = As + (wm*64 + (lane&15))*BK + (lane>>4)*8;
  const short* bbase = Bs + (wn*64 + (lane&15))*BK + (lane>>4)*8;

  for (int k0 = 0; k0 < K; k0 += BK) {
    __syncthreads();
    gload_lds16(a0 + k0, As + wid*512);
    gload_lds16(a1 + k0, As + 2048 + wid*512);
    gload_lds16(b0 + k0, Bs + wid*512);
    gload_lds16(b1 + k0, Bs + 2048 + wid*512);
    __syncthreads();
    s16x8 af[4], bff[4];
    for (int f = 0; f < 4; ++f) {
      af[f]  = *(const s16x8*)(abase + f*16*BK);
      bff[f] = *(const s16x8*)(bbase + f*16*BK);
    }
    for (int i = 0; i < 4; ++i)
      for (int j = 0; j < 4; ++j)
        acc[i][j] = __builtin_amdgcn_mfma_f32_16x16x32_bf16(af[i], bff[j], acc[i][j], 0, 0, 0);
  }

  int col = lane & 15, rb = (lane >> 4) * 4;
  for (int fi = 0; fi < 4; ++fi) for (int fj = 0; fj < 4; ++fj) {
    int n = bn*BN + wn*64 + fj*16 + col;
    float bias = n < 1024 ? bfz[n] : (n < 2048 ? bfr[n-1024] : bfh[n-2048]);
    f32x4 c = acc[fi][fj];
    for (int i = 0; i < 4; ++i) {
      int m = bm*BM + wm*64 + fi*16 + rb + i;
      int bb = m >> 9, tt = m & 511;
      X[((size_t)tt*64 + bb)*3072 + n] = f2bf(c[i] + bias);
    }
  }
}

// ---------------- global barrier: monotone counter, no fences ----------------
__device__ __forceinline__ void gbar(int* cnt, int target) {
  // __syncthreads() drains vmcnt(0) before s_barrier, so all agent-scope
  // data stores (write-through to LLC) are complete before the arrival add.
  __syncthreads();
  if (threadIdx.x == 0) {
    __hip_atomic_fetch_add(cnt, 1, __ATOMIC_RELAXED, __HIP_MEMORY_SCOPE_AGENT);
    while (__hip_atomic_load(cnt, __ATOMIC_RELAXED, __HIP_MEMORY_SCOPE_AGENT) < target) { }
  }
  __syncthreads();
}

// ---------------- persistent recurrence: 64 wgs x 256 thr ----------------
// wg w owns columns J = [w*16, w*16+16) for z, r, AND h -> z and f32 h live in
// registers; only bf16 h and bf16 r*h cross workgroups (via LLC atomics).
__global__ __launch_bounds__(256) void recur(
  const short* __restrict__ X,    // [512][64][3072] bf16 (bias included)
  const short* __restrict__ Wzr,  // [2048][1024] bf16
  const short* __restrict__ Wh,   // [1024][1024] bf16
  const float* __restrict__ h0,
  const float* __restrict__ buz, const float* __restrict__ bur, const float* __restrict__ buh,
  short* hb,                      // [2][64][1024] bf16 h (double-buffered)
  short* rh,                      // [64][1024] bf16 r*h
  float* y, float* hlast, int* bar)
{
  int wg = blockIdx.x, tid = threadIdx.x, lane = tid & 63, wid = tid >> 6;
  int col = lane & 15, rb = (lane >> 4) * 4, kfo = (lane >> 4) * 8;
  int arow = wid*16 + col;
  int j = wg*16 + col;
  int b0 = wid*16 + rb;

  float bz = buz[j], br = bur[j], bh = buh[j];
  float hreg[4], zreg[4];
  for (int i = 0; i < 4; ++i) hreg[i] = h0[(b0+i)*1024 + j];

  const short* bpz = Wzr + (size_t)j*1024 + kfo;
  const short* bpr = Wzr + (size_t)(1024+j)*1024 + kfo;
  const short* bph = Wh  + (size_t)j*1024 + kfo;

  int target = 64;
  for (int t = 0; t < 512; ++t) {
    const short* hbc = hb + (t&1)*65536;
    short* hbn = hb + ((t&1)^1)*65536;
    const short* Xt = X + (size_t)t*196608;

    // prefetch X for this step (normal cached loads; X is read-only here)
    float xz[4], xr[4], xh[4];
    for (int i = 0; i < 4; ++i) {
      const short* xp = Xt + (size_t)(b0+i)*3072 + j;
      xz[i] = bf2f(xp[0]);
      xr[i] = bf2f(xp[1024]);
      xh[i] = bf2f(xp[2048]);
    }

    { // phase 1: S_z, S_r for local 16 cols; z->regs, r*h -> rh (coherent)
      f32x4 acz = {0.f,0.f,0.f,0.f}, acr = {0.f,0.f,0.f,0.f};
      const short* ap = hbc + arow*1024 + kfo;
      #pragma unroll 4
      for (int k0 = 0; k0 < 1024; k0 += 32) {
        s16x8 av = loadA16(ap + k0);
        s16x8 vz = *(const s16x8*)(bpz + k0);
        s16x8 vr = *(const s16x8*)(bpr + k0);
        acz = __builtin_amdgcn_mfma_f32_16x16x32_bf16(av, vz, acz, 0,0,0);
        acr = __builtin_amdgcn_mfma_f32_16x16x32_bf16(av, vr, acr, 0,0,0);
      }
      for (int i = 0; i < 4; ++i) {
        zreg[i] = sigm(xz[i] + acz[i] + bz);
        float r = sigm(xr[i] + acr[i] + br);
        __hip_atomic_store(rh + (b0+i)*1024 + j, f2bf(r * hreg[i]),
                           __ATOMIC_RELAXED, __HIP_MEMORY_SCOPE_AGENT);
      }
    }
    gbar(bar, target); target += 64;

    { // phase 2: S_h over rh; combine in registers; write y / h
      f32x4 ach = {0.f,0.f,0.f,0.f};
      const short* ap = rh + arow*1024 + kfo;
      #pragma unroll 4
      for (int k0 = 0; k0 < 1024; k0 += 32) {
        s16x8 av = loadA16(ap + k0);
        s16x8 vh = *(const s16x8*)(bph + k0);
        ach = __builtin_amdgcn_mfma_f32_16x16x32_bf16(av, vh, ach, 0,0,0);
      }
      for (int i = 0; i < 4; ++i) {
        float s  = xh[i] + ach[i] + bh;
        float hh = s * sigm(s);
        float z  = zreg[i];
        float hn = (1.0f - z)*hreg[i] + z*hh;
        hreg[i] = hn;
        __builtin_nontemporal_store(hn, y + ((size_t)(b0+i)*512 + t)*1024 + j);
        __hip_atomic_store(hbn + (b0+i)*1024 + j, f2bf(hn),
                           __ATOMIC_RELAXED, __HIP_MEMORY_SCOPE_AGENT);
      }
      if (t == 511)
        for (int i = 0; i < 4; ++i) hlast[(b0+i)*1024 + j] = hreg[i];
    }
    gbar(bar, target); target += 64;
  }
}

extern "C" void kernel_launch(void* const* d_in, const int* in_sizes, int n_in,
                              void* d_out, int out_size, void* d_ws, size_t ws_size,
                              hipStream_t stream) {
  const float* x   = (const float*)d_in[0];
  const float* h0  = (const float*)d_in[1];
  const float* Wfz = (const float*)d_in[2];
  const float* bfz = (const float*)d_in[3];
  const float* Wfr = (const float*)d_in[4];
  const float* bfr = (const float*)d_in[5];
  const float* Wfh = (const float*)d_in[6];
  const float* bfh = (const float*)d_in[7];
  const float* Wuz = (const float*)d_in[8];
  const float* buz = (const float*)d_in[9];
  const float* Wur = (const float*)d_in[10];
  const float* bur = (const float*)d_in[11];
  const float* Wuh = (const float*)d_in[12];
  const float* buh = (const float*)d_in[13];

  char* ws = (char*)d_ws;
  short* Xb  = (short*)(ws);                  // 201326592 B  [512][64][3072] bf16
  short* xb  = (short*)(ws + 201326592);      //  67108864 B  x bf16
  short* Wf  = (short*)(ws + 268435456);      //   6291456 B  [3072][1024]
  short* Wzr = (short*)(ws + 274726912);      //   4194304 B  [2048][1024]
  short* Wh  = (short*)(ws + 278921216);      //   2097152 B  [1024][1024]
  short* hb  = (short*)(ws + 281018368);      //    262144 B  [2][64][1024] bf16
  short* rh  = (short*)(ws + 281280512);      //    131072 B  [64][1024] bf16
  int*   bar = (int*)(ws + 281411584);        //    barrier counter

  float* y = (float*)d_out;
  float* hlast = y + 33554432;                // 64*512*1024

  hipMemsetAsync(bar, 0, 64, stream);
  prep<<<2048, 256, 0, stream>>>(x, Wfz, Wfr, Wfh, Wuz, Wur, Wuh, h0, xb, Wf, Wzr, Wh, hb);
  gemm_x<<<6144, 256, 0, stream>>>(xb, Wf, bfz, bfr, bfh, Xb);
  recur<<<64, 256, 0, stream>>>(Xb, Wzr, Wh, h0, buz, bur, buh, hb, rh, y, hlast, bar);
}

// Round 3
// 8215.045 us; speedup vs baseline: 2.2520x; 1.9545x over previous
//
#include <hip/hip_runtime.h>
#include <hip/hip_bf16.h>

typedef short s16x8 __attribute__((ext_vector_type(8)));
typedef float f32x4 __attribute__((ext_vector_type(4)));

__device__ __forceinline__ float bf2f(unsigned short s) {
  union { unsigned int u; float f; } c; c.u = ((unsigned int)s) << 16; return c.f;
}
__device__ __forceinline__ short f2bf(float f) {
  union { float f; unsigned int u; } c; c.f = f;
  unsigned int r = (c.u + 0x7fffu + ((c.u >> 16) & 1u)) >> 16;
  return (short)(unsigned short)r;
}
__device__ __forceinline__ float sigm(float x) { return 1.0f / (1.0f + __expf(-x)); }

__device__ __forceinline__ void gload_lds16(const short* g, short* l) {
  __builtin_amdgcn_global_load_lds((const __attribute__((address_space(1))) void*)g,
                                   (__attribute__((address_space(3))) void*)l, 16, 0, 0);
}

// batched coherent loads: 8x global_load_dwordx4 sc0 sc1 (bypass L1/L2, read LLC),
// fully pipelined; caller does s_waitcnt vmcnt(0) + sched_barrier(0) before use.
__device__ __forceinline__ void cload8(const short* p,
    s16x8& d0, s16x8& d1, s16x8& d2, s16x8& d3,
    s16x8& d4, s16x8& d5, s16x8& d6, s16x8& d7)
{
  asm volatile(
    "global_load_dwordx4 %0, %[p], off sc0 sc1\n\t"
    "global_load_dwordx4 %1, %[p], off offset:64 sc0 sc1\n\t"
    "global_load_dwordx4 %2, %[p], off offset:128 sc0 sc1\n\t"
    "global_load_dwordx4 %3, %[p], off offset:192 sc0 sc1\n\t"
    "global_load_dwordx4 %4, %[p], off offset:256 sc0 sc1\n\t"
    "global_load_dwordx4 %5, %[p], off offset:320 sc0 sc1\n\t"
    "global_load_dwordx4 %6, %[p], off offset:384 sc0 sc1\n\t"
    "global_load_dwordx4 %7, %[p], off offset:448 sc0 sc1"
    : "=&v"(d0), "=&v"(d1), "=&v"(d2), "=&v"(d3),
      "=&v"(d4), "=&v"(d5), "=&v"(d6), "=&v"(d7)
    : [p]"v"(p));
}

// ---------------- prep: f32 -> bf16 conversions + h init ----------------
__global__ void prep(const float* __restrict__ x,
                     const float* __restrict__ Wfz, const float* __restrict__ Wfr, const float* __restrict__ Wfh,
                     const float* __restrict__ Wuz, const float* __restrict__ Wur, const float* __restrict__ Wuh,
                     const float* __restrict__ h0,
                     short* __restrict__ xb, short* __restrict__ Wf, short* __restrict__ Wzr,
                     short* __restrict__ Wh, short* __restrict__ hb)
{
  const long NX = 33554432L;      // 64*512*1024
  const long NW = 1048576L;       // 1024*1024
  const long TOT = NX + 6*NW + 65536L;
  long stride = (long)gridDim.x * blockDim.x;
  for (long p = (long)blockIdx.x * blockDim.x + threadIdx.x; p < TOT; p += stride) {
    if (p < NX) { xb[p] = f2bf(x[p]); }
    else if (p < NX + 3*NW) {
      long q = p - NX;
      float v = q < NW ? Wfz[q] : (q < 2*NW ? Wfr[q-NW] : Wfh[q-2*NW]);
      Wf[q] = f2bf(v);
    } else if (p < NX + 5*NW) {
      long q = p - NX - 3*NW;
      float v = q < NW ? Wuz[q] : Wur[q-NW];
      Wzr[q] = f2bf(v);
    } else if (p < NX + 6*NW) {
      long q = p - NX - 5*NW;
      Wh[q] = f2bf(Wuh[q]);
    } else {
      long q = p - NX - 6*NW;
      hb[q] = f2bf(h0[q]);
    }
  }
}

// ---------------- input GEMM: X[t][b][n] = bf16( x@WfT + bias ) ----------------
__global__ __launch_bounds__(256) void gemm_x(const short* __restrict__ A, const short* __restrict__ Bw,
    const float* __restrict__ bfz, const float* __restrict__ bfr, const float* __restrict__ bfh,
    short* __restrict__ X)
{
  constexpr int M = 32768, K = 1024;
  constexpr int BM = 128, BN = 128, BK = 32;
  __shared__ __align__(16) short As[BM*BK];
  __shared__ __align__(16) short Bs[BN*BK];
  int tid = threadIdx.x, lane = tid & 63, wid = tid >> 6;
  int bm = blockIdx.x % (M/BM), bn = blockIdx.x / (M/BM);
  int wm = wid >> 1, wn = wid & 1;

  f32x4 acc[4][4];
  for (int i = 0; i < 4; ++i) for (int j = 0; j < 4; ++j) acc[i][j] = f32x4{0.f,0.f,0.f,0.f};

  int r0 = tid >> 2,        kc0 = (tid & 3) * 8;
  int r1 = (256+tid) >> 2,  kc1 = ((256+tid) & 3) * 8;
  const short* a0 = A  + (size_t)(bm*BM + r0)*K + kc0;
  const short* a1 = A  + (size_t)(bm*BM + r1)*K + kc1;
  const short* b0 = Bw + (size_t)(bn*BN + r0)*K + kc0;
  const short* b1 = Bw + (size_t)(bn*BN + r1)*K + kc1;

  const short* abase = As + (wm*64 + (lane&15))*BK + (lane>>4)*8;
  const short* bbase = Bs + (wn*64 + (lane&15))*BK + (lane>>4)*8;

  for (int k0 = 0; k0 < K; k0 += BK) {
    __syncthreads();
    gload_lds16(a0 + k0, As + wid*512);
    gload_lds16(a1 + k0, As + 2048 + wid*512);
    gload_lds16(b0 + k0, Bs + wid*512);
    gload_lds16(b1 + k0, Bs + 2048 + wid*512);
    __syncthreads();
    s16x8 af[4], bff[4];
    for (int f = 0; f < 4; ++f) {
      af[f]  = *(const s16x8*)(abase + f*16*BK);
      bff[f] = *(const s16x8*)(bbase + f*16*BK);
    }
    for (int i = 0; i < 4; ++i)
      for (int j = 0; j < 4; ++j)
        acc[i][j] = __builtin_amdgcn_mfma_f32_16x16x32_bf16(af[i], bff[j], acc[i][j], 0, 0, 0);
  }

  int col = lane & 15, rb = (lane >> 4) * 4;
  for (int fi = 0; fi < 4; ++fi) for (int fj = 0; fj < 4; ++fj) {
    int n = bn*BN + wn*64 + fj*16 + col;
    float bias = n < 1024 ? bfz[n] : (n < 2048 ? bfr[n-1024] : bfh[n-2048]);
    f32x4 c = acc[fi][fj];
    for (int i = 0; i < 4; ++i) {
      int m = bm*BM + wm*64 + fi*16 + rb + i;
      int bb = m >> 9, tt = m & 511;
      X[((size_t)tt*64 + bb)*3072 + n] = f2bf(c[i] + bias);
    }
  }
}

// ---------------- global barrier: per-wg flags, broadcast poll ----------------
__device__ __forceinline__ void gbar(int* flags, int wg, int seq) {
  asm volatile("s_waitcnt vmcnt(0)" ::: "memory");  // own wave's coherent stores at LLC
  __syncthreads();                                  // all waves in wg drained
  if (threadIdx.x < 64) {
    if (threadIdx.x == 0)
      __hip_atomic_store(flags + wg, seq, __ATOMIC_RELAXED, __HIP_MEMORY_SCOPE_AGENT);
    int v;
    do {
      v = __hip_atomic_load(flags + (int)threadIdx.x, __ATOMIC_RELAXED, __HIP_MEMORY_SCOPE_AGENT);
    } while (__any(v < seq));
  }
  __syncthreads();
}

// ---------------- persistent recurrence: 64 wgs x 256 thr ----------------
// wg owns 16 hidden columns for z, r, h. Weights in LDS (96KB). h / r*h cross
// wgs via LLC (sc0sc1 batched loads / atomic stores). 2 flag-barriers per step.
__global__ __launch_bounds__(256) void recur(
  const short* __restrict__ X,    // [512][64][3072] bf16 (bias included)
  const short* __restrict__ Wzr,  // [2048][1024] bf16
  const short* __restrict__ Wh,   // [1024][1024] bf16
  const float* __restrict__ h0,
  const float* __restrict__ buz, const float* __restrict__ bur, const float* __restrict__ buh,
  short* hb,                      // [2][64][1024] bf16 h (double-buffered)
  short* rh,                      // [64][1024] bf16 r*h
  float* y, float* hlast, int* flags)
{
  constexpr int WROW = 1032;      // shorts per LDS weight row (2064 B: +16B pad -> 2-way banks, free)
  __shared__ __align__(16) short Wl[48 * WROW];   // rows 0-15: Wuz(j), 16-31: Wur(j), 32-47: Wuh(j)

  int wg = blockIdx.x, tid = threadIdx.x, lane = tid & 63, wid = tid >> 6;
  int col = lane & 15, rb = (lane >> 4) * 4, kfo = (lane >> 4) * 8;
  int arow = wid*16 + col;        // A-operand row (batch index) for MFMA
  int j = wg*16 + col;            // owned hidden column
  int b0 = wid*16 + rb;           // C-fragment rows b0..b0+3

  // ---- stage weights to LDS (once) ----
  for (int c = tid; c < 48*128; c += 256) {
    int row = c >> 7, o16 = c & 127;
    int gc = wg*16 + (row & 15);
    const short* src = (row < 16) ? (Wzr + (size_t)gc*1024)
                     : (row < 32) ? (Wzr + (size_t)(1024+gc)*1024)
                                  : (Wh  + (size_t)gc*1024);
    *(s16x8*)(&Wl[row*WROW + o16*8]) = *(const s16x8*)(src + o16*8);
  }

  float bz = buz[j], br = bur[j], bh = buh[j];
  float hreg[4], zreg[4];
  #pragma unroll
  for (int i = 0; i < 4; ++i) hreg[i] = h0[(b0+i)*1024 + j];

  // prologue: X_0 into regs (raw bf16 bits); [0..3]=xz, [4..7]=xr, [8..11]=xh
  unsigned short xs[12], xn[12];
  #pragma unroll
  for (int i = 0; i < 4; ++i) {
    const unsigned short* xp = (const unsigned short*)X + ((size_t)(b0+i))*3072 + j;
    xs[i] = xp[0]; xs[4+i] = xp[1024]; xs[8+i] = xp[2048];
  }
  __syncthreads();   // LDS weights ready

  const short* wlz = Wl + col*WROW + kfo;
  const short* wlr = Wl + (16+col)*WROW + kfo;
  const short* wlh = Wl + (32+col)*WROW + kfo;

  int seq = 1;
  for (int t = 0; t < 512; ++t) {
    const short* hbc = hb + (t&1)*65536;
    short* hbn = hb + ((t&1)^1)*65536;

    { // ---- phase 1: z, r for own 16 cols; store rh ----
      const short* ap = hbc + arow*1024 + kfo;
      s16x8 ah[32];
      cload8(ap,     ah[0], ah[1], ah[2], ah[3], ah[4], ah[5], ah[6], ah[7]);
      cload8(ap+256, ah[8], ah[9], ah[10],ah[11],ah[12],ah[13],ah[14],ah[15]);
      cload8(ap+512, ah[16],ah[17],ah[18],ah[19],ah[20],ah[21],ah[22],ah[23]);
      cload8(ap+768, ah[24],ah[25],ah[26],ah[27],ah[28],ah[29],ah[30],ah[31]);
      // prefetch X_{t+1} in the same load shadow
      int tn = (t+1) & 511;
      #pragma unroll
      for (int i = 0; i < 4; ++i) {
        const unsigned short* xp = (const unsigned short*)X + ((size_t)tn*64 + (b0+i))*3072 + j;
        xn[i] = xp[0]; xn[4+i] = xp[1024]; xn[8+i] = xp[2048];
      }
      asm volatile("s_waitcnt vmcnt(0)" ::: "memory");
      __builtin_amdgcn_sched_barrier(0);
      f32x4 acz = {0.f,0.f,0.f,0.f}, acr = {0.f,0.f,0.f,0.f};
      #pragma unroll
      for (int n = 0; n < 32; ++n) {
        s16x8 vz = *(const s16x8*)(wlz + n*32);
        s16x8 vr = *(const s16x8*)(wlr + n*32);
        acz = __builtin_amdgcn_mfma_f32_16x16x32_bf16(ah[n], vz, acz, 0,0,0);
        acr = __builtin_amdgcn_mfma_f32_16x16x32_bf16(ah[n], vr, acr, 0,0,0);
      }
      #pragma unroll
      for (int i = 0; i < 4; ++i) {
        zreg[i] = sigm(bf2f(xs[i]) + acz[i] + bz);
        float r = sigm(bf2f(xs[4+i]) + acr[i] + br);
        __hip_atomic_store(rh + (b0+i)*1024 + j, f2bf(r * hreg[i]),
                           __ATOMIC_RELAXED, __HIP_MEMORY_SCOPE_AGENT);
      }
    }
    gbar(flags, wg, seq); ++seq;

    { // ---- phase 2: h_hat for own 16 cols; combine; write y/h ----
      const short* ap = rh + arow*1024 + kfo;
      s16x8 ah[32];
      cload8(ap,     ah[0], ah[1], ah[2], ah[3], ah[4], ah[5], ah[6], ah[7]);
      cload8(ap+256, ah[8], ah[9], ah[10],ah[11],ah[12],ah[13],ah[14],ah[15]);
      cload8(ap+512, ah[16],ah[17],ah[18],ah[19],ah[20],ah[21],ah[22],ah[23]);
      cload8(ap+768, ah[24],ah[25],ah[26],ah[27],ah[28],ah[29],ah[30],ah[31]);
      asm volatile("s_waitcnt vmcnt(0)" ::: "memory");
      __builtin_amdgcn_sched_barrier(0);
      f32x4 ach = {0.f,0.f,0.f,0.f};
      #pragma unroll
      for (int n = 0; n < 32; ++n) {
        s16x8 vh = *(const s16x8*)(wlh + n*32);
        ach = __builtin_amdgcn_mfma_f32_16x16x32_bf16(ah[n], vh, ach, 0,0,0);
      }
      #pragma unroll
      for (int i = 0; i < 4; ++i) {
        float s  = bf2f(xs[8+i]) + ach[i] + bh;
        float hh = s * sigm(s);
        float hn = (1.0f - zreg[i])*hreg[i] + zreg[i]*hh;
        hreg[i] = hn;
        __builtin_nontemporal_store(hn, y + ((size_t)(b0+i)*512 + t)*1024 + j);
        __hip_atomic_store(hbn + (b0+i)*1024 + j, f2bf(hn),
                           __ATOMIC_RELAXED, __HIP_MEMORY_SCOPE_AGENT);
      }
      if (t == 511) {
        #pragma unroll
        for (int i = 0; i < 4; ++i) hlast[(b0+i)*1024 + j] = hreg[i];
      }
    }
    gbar(flags, wg, seq); ++seq;

    #pragma unroll
    for (int q = 0; q < 12; ++q) xs[q] = xn[q];
  }
}

extern "C" void kernel_launch(void* const* d_in, const int* in_sizes, int n_in,
                              void* d_out, int out_size, void* d_ws, size_t ws_size,
                              hipStream_t stream) {
  const float* x   = (const float*)d_in[0];
  const float* h0  = (const float*)d_in[1];
  const float* Wfz = (const float*)d_in[2];
  const float* bfz = (const float*)d_in[3];
  const float* Wfr = (const float*)d_in[4];
  const float* bfr = (const float*)d_in[5];
  const float* Wfh = (const float*)d_in[6];
  const float* bfh = (const float*)d_in[7];
  const float* Wuz = (const float*)d_in[8];
  const float* buz = (const float*)d_in[9];
  const float* Wur = (const float*)d_in[10];
  const float* bur = (const float*)d_in[11];
  const float* Wuh = (const float*)d_in[12];
  const float* buh = (const float*)d_in[13];

  char* ws = (char*)d_ws;
  short* Xb  = (short*)(ws);                  // 201326592 B  [512][64][3072] bf16
  short* xb  = (short*)(ws + 201326592);      //  67108864 B  x bf16
  short* Wf  = (short*)(ws + 268435456);      //   6291456 B  [3072][1024]
  short* Wzr = (short*)(ws + 274726912);      //   4194304 B  [2048][1024]
  short* Wh  = (short*)(ws + 278921216);      //   2097152 B  [1024][1024]
  short* hb  = (short*)(ws + 281018368);      //    262144 B  [2][64][1024] bf16
  short* rh  = (short*)(ws + 281280512);      //    131072 B  [64][1024] bf16
  int*   bar = (int*)(ws + 281411584);        //    256 B barrier flags[64]

  float* y = (float*)d_out;
  float* hlast = y + 33554432;                // 64*512*1024

  hipMemsetAsync(bar, 0, 256, stream);
  prep<<<2048, 256, 0, stream>>>(x, Wfz, Wfr, Wfh, Wuz, Wur, Wuh, h0, xb, Wf, Wzr, Wh, hb);
  gemm_x<<<6144, 256, 0, stream>>>(xb, Wf, bfz, bfr, bfh, Xb);
  recur<<<64, 256, 0, stream>>>(Xb, Wzr, Wh, h0, buz, bur, buh, hb, rh, y, hlast, bar);
}

// Round 4
// 3804.331 us; speedup vs baseline: 4.8629x; 2.1594x over previous
//
#include <hip/hip_runtime.h>
#include <hip/hip_bf16.h>

typedef short s16x8 __attribute__((ext_vector_type(8)));
typedef float f32x4 __attribute__((ext_vector_type(4)));

__device__ __forceinline__ float bf2f(unsigned short s) {
  union { unsigned int u; float f; } c; c.u = ((unsigned int)s) << 16; return c.f;
}
__device__ __forceinline__ short f2bf(float f) {
  union { float f; unsigned int u; } c; c.f = f;
  unsigned int r = (c.u + 0x7fffu + ((c.u >> 16) & 1u)) >> 16;
  return (short)(unsigned short)r;
}
__device__ __forceinline__ float sigm(float x) { return 1.0f / (1.0f + __expf(-x)); }

__device__ __forceinline__ void gload_lds16(const short* g, short* l) {
  __builtin_amdgcn_global_load_lds((const __attribute__((address_space(1))) void*)g,
                                   (__attribute__((address_space(3))) void*)l, 16, 0, 0);
}

// batched coherent loads: 8x global_load_dwordx4 sc0 sc1 (bypass L1/L2, read LLC)
__device__ __forceinline__ void cload8(const short* p,
    s16x8& d0, s16x8& d1, s16x8& d2, s16x8& d3,
    s16x8& d4, s16x8& d5, s16x8& d6, s16x8& d7)
{
  asm volatile(
    "global_load_dwordx4 %0, %[p], off sc0 sc1\n\t"
    "global_load_dwordx4 %1, %[p], off offset:64 sc0 sc1\n\t"
    "global_load_dwordx4 %2, %[p], off offset:128 sc0 sc1\n\t"
    "global_load_dwordx4 %3, %[p], off offset:192 sc0 sc1\n\t"
    "global_load_dwordx4 %4, %[p], off offset:256 sc0 sc1\n\t"
    "global_load_dwordx4 %5, %[p], off offset:320 sc0 sc1\n\t"
    "global_load_dwordx4 %6, %[p], off offset:384 sc0 sc1\n\t"
    "global_load_dwordx4 %7, %[p], off offset:448 sc0 sc1"
    : "=&v"(d0), "=&v"(d1), "=&v"(d2), "=&v"(d3),
      "=&v"(d4), "=&v"(d5), "=&v"(d6), "=&v"(d7)
    : [p]"v"(p) : "memory");
}

// ---------------- prep ----------------
__global__ void prep(const float* __restrict__ x,
                     const float* __restrict__ Wfz, const float* __restrict__ Wfr, const float* __restrict__ Wfh,
                     const float* __restrict__ Wuz, const float* __restrict__ Wur, const float* __restrict__ Wuh,
                     const float* __restrict__ h0,
                     short* __restrict__ xb, short* __restrict__ Wf, short* __restrict__ Wzr,
                     short* __restrict__ Wh, short* __restrict__ hb)
{
  const long NX = 33554432L;
  const long NW = 1048576L;
  const long TOT = NX + 6*NW + 65536L;
  long stride = (long)gridDim.x * blockDim.x;
  for (long p = (long)blockIdx.x * blockDim.x + threadIdx.x; p < TOT; p += stride) {
    if (p < NX) { xb[p] = f2bf(x[p]); }
    else if (p < NX + 3*NW) {
      long q = p - NX;
      float v = q < NW ? Wfz[q] : (q < 2*NW ? Wfr[q-NW] : Wfh[q-2*NW]);
      Wf[q] = f2bf(v);
    } else if (p < NX + 5*NW) {
      long q = p - NX - 3*NW;
      float v = q < NW ? Wuz[q] : Wur[q-NW];
      Wzr[q] = f2bf(v);
    } else if (p < NX + 6*NW) {
      long q = p - NX - 5*NW;
      Wh[q] = f2bf(Wuh[q]);
    } else {
      long q = p - NX - 6*NW;
      hb[q] = f2bf(h0[q]);
    }
  }
}

// ---------------- input GEMM ----------------
__global__ __launch_bounds__(256) void gemm_x(const short* __restrict__ A, const short* __restrict__ Bw,
    const float* __restrict__ bfz, const float* __restrict__ bfr, const float* __restrict__ bfh,
    short* __restrict__ X)
{
  constexpr int M = 32768, K = 1024;
  constexpr int BM = 128, BN = 128, BK = 32;
  __shared__ __align__(16) short As[BM*BK];
  __shared__ __align__(16) short Bs[BN*BK];
  int tid = threadIdx.x, lane = tid & 63, wid = tid >> 6;
  int bm = blockIdx.x % (M/BM), bn = blockIdx.x / (M/BM);
  int wm = wid >> 1, wn = wid & 1;

  f32x4 acc[4][4];
  for (int i = 0; i < 4; ++i) for (int j = 0; j < 4; ++j) acc[i][j] = f32x4{0.f,0.f,0.f,0.f};

  int r0 = tid >> 2,        kc0 = (tid & 3) * 8;
  int r1 = (256+tid) >> 2,  kc1 = ((256+tid) & 3) * 8;
  const short* a0 = A  + (size_t)(bm*BM + r0)*K + kc0;
  const short* a1 = A  + (size_t)(bm*BM + r1)*K + kc1;
  const short* b0 = Bw + (size_t)(bn*BN + r0)*K + kc0;
  const short* b1 = Bw + (size_t)(bn*BN + r1)*K + kc1;

  const short* abase = As + (wm*64 + (lane&15))*BK + (lane>>4)*8;
  const short* bbase = Bs + (wn*64 + (lane&15))*BK + (lane>>4)*8;

  for (int k0 = 0; k0 < K; k0 += BK) {
    __syncthreads();
    gload_lds16(a0 + k0, As + wid*512);
    gload_lds16(a1 + k0, As + 2048 + wid*512);
    gload_lds16(b0 + k0, Bs + wid*512);
    gload_lds16(b1 + k0, Bs + 2048 + wid*512);
    __syncthreads();
    s16x8 af[4], bff[4];
    for (int f = 0; f < 4; ++f) {
      af[f]  = *(const s16x8*)(abase + f*16*BK);
      bff[f] = *(const s16x8*)(bbase + f*16*BK);
    }
    for (int i = 0; i < 4; ++i)
      for (int j = 0; j < 4; ++j)
        acc[i][j] = __builtin_amdgcn_mfma_f32_16x16x32_bf16(af[i], bff[j], acc[i][j], 0, 0, 0);
  }

  int col = lane & 15, rb = (lane >> 4) * 4;
  for (int fi = 0; fi < 4; ++fi) for (int fj = 0; fj < 4; ++fj) {
    int n = bn*BN + wn*64 + fj*16 + col;
    float bias = n < 1024 ? bfz[n] : (n < 2048 ? bfr[n-1024] : bfh[n-2048]);
    f32x4 c = acc[fi][fj];
    for (int i = 0; i < 4; ++i) {
      int m = bm*BM + wm*64 + fi*16 + rb + i;
      int bb = m >> 9, tt = m & 511;
      X[((size_t)tt*64 + bb)*3072 + n] = f2bf(c[i] + bias);
    }
  }
}

// counted-vmcnt chunk fences
#define WAITV(N) asm volatile("s_waitcnt vmcnt(" #N ")" ::: "memory"); \
                 __builtin_amdgcn_sched_barrier(0);

// ---------------- persistent recurrence: 256 wgs x 64 thr (1 wave each) ----------------
// wg = bg*64+cg ... wait: cg = wg&63 col-group (16 cols), bg = wg>>6 batch-group (16 rows).
// 4 independent barrier domains (batch rows never mix). Weights LDS-resident (97KB -> 1 wg/CU).
__global__ __launch_bounds__(64, 1) void recur(
  const short* __restrict__ X,    // [512][64][3072] bf16
  const short* __restrict__ Wzr,  // [2048][1024] bf16
  const short* __restrict__ Wh,   // [1024][1024] bf16
  const float* __restrict__ h0,
  const float* __restrict__ buz, const float* __restrict__ bur, const float* __restrict__ buh,
  short* hb,                      // [2][64][1024] bf16 h
  short* rh,                      // [64][1024] bf16 r*h
  float* y, float* hlast, int* flags)
{
  constexpr int WROW = 1032;
  __shared__ __align__(16) short Wl[48 * WROW];   // 99072 B -> 1 wg per CU

  int wg = blockIdx.x;
  int cg = wg & 63, bg = wg >> 6;
  int lane = threadIdx.x;
  int col = lane & 15, hi = lane >> 4;
  int rb = hi*4, kfo = hi*8;
  int j  = cg*16 + col;           // owned hidden column
  int b0 = bg*16 + rb;            // C rows (batch)
  int arow = bg*16 + col;         // A row (batch) for MFMA fragment

  // stage this wg's 48 weight rows to LDS
  for (int c = lane; c < 48*128; c += 64) {
    int row = c >> 7, o16 = c & 127;
    int gc = cg*16 + (row & 15);
    const short* src = (row < 16) ? (Wzr + (size_t)gc*1024)
                     : (row < 32) ? (Wzr + (size_t)(1024+gc)*1024)
                                  : (Wh  + (size_t)gc*1024);
    *(s16x8*)(&Wl[row*WROW + o16*8]) = *(const s16x8*)(src + o16*8);
  }

  float bz = buz[j], br = bur[j], bh = buh[j];
  float hreg[4], zreg[4];
  #pragma unroll
  for (int i = 0; i < 4; ++i) hreg[i] = h0[(b0+i)*1024 + j];

  unsigned short xs[12], xn[12];
  #pragma unroll
  for (int i = 0; i < 4; ++i) {
    const unsigned short* xp = (const unsigned short*)X + ((size_t)(b0+i))*3072 + j;
    xs[i] = xp[0]; xs[4+i] = xp[1024]; xs[8+i] = xp[2048];
  }
  __syncthreads();   // LDS weights visible

  const short* wlz = Wl + col*WROW + kfo;
  const short* wlr = Wl + (16+col)*WROW + kfo;
  const short* wlh = Wl + (32+col)*WROW + kfo;
  int* fslot = flags + wg*32;
  int* fpoll = flags + ((bg<<6) + lane)*32;

  int seq = 1;
  for (int t = 0; t < 512; ++t) {
    const short* hbc = hb + (t&1)*65536;
    short* hbn = hb + ((t&1)^1)*65536;

    { // ---- phase 1: z, r ----
      const short* ap = hbc + (size_t)arow*1024 + kfo;
      s16x8 ah[32];
      cload8(ap,     ah[0], ah[1], ah[2], ah[3], ah[4], ah[5], ah[6], ah[7]);
      cload8(ap+256, ah[8], ah[9], ah[10],ah[11],ah[12],ah[13],ah[14],ah[15]);
      cload8(ap+512, ah[16],ah[17],ah[18],ah[19],ah[20],ah[21],ah[22],ah[23]);
      cload8(ap+768, ah[24],ah[25],ah[26],ah[27],ah[28],ah[29],ah[30],ah[31]);
      // X_{t+1} prefetch, issued after A-loads (counts never invalidate waits below)
      int tn = (t+1) & 511;
      #pragma unroll
      for (int i = 0; i < 4; ++i) {
        const unsigned short* xp = (const unsigned short*)X + ((size_t)tn*64 + (b0+i))*3072 + j;
        xn[i] = xp[0]; xn[4+i] = xp[1024]; xn[8+i] = xp[2048];
      }
      f32x4 acz = {0.f,0.f,0.f,0.f}, acr = {0.f,0.f,0.f,0.f};
      WAITV(24)
      #pragma unroll
      for (int n = 0; n < 8; ++n) {
        s16x8 vz = *(const s16x8*)(wlz + n*32);
        s16x8 vr = *(const s16x8*)(wlr + n*32);
        acz = __builtin_amdgcn_mfma_f32_16x16x32_bf16(ah[n], vz, acz, 0,0,0);
        acr = __builtin_amdgcn_mfma_f32_16x16x32_bf16(ah[n], vr, acr, 0,0,0);
      }
      WAITV(16)
      #pragma unroll
      for (int n = 8; n < 16; ++n) {
        s16x8 vz = *(const s16x8*)(wlz + n*32);
        s16x8 vr = *(const s16x8*)(wlr + n*32);
        acz = __builtin_amdgcn_mfma_f32_16x16x32_bf16(ah[n], vz, acz, 0,0,0);
        acr = __builtin_amdgcn_mfma_f32_16x16x32_bf16(ah[n], vr, acr, 0,0,0);
      }
      WAITV(8)
      #pragma unroll
      for (int n = 16; n < 24; ++n) {
        s16x8 vz = *(const s16x8*)(wlz + n*32);
        s16x8 vr = *(const s16x8*)(wlr + n*32);
        acz = __builtin_amdgcn_mfma_f32_16x16x32_bf16(ah[n], vz, acz, 0,0,0);
        acr = __builtin_amdgcn_mfma_f32_16x16x32_bf16(ah[n], vr, acr, 0,0,0);
      }
      WAITV(0)
      #pragma unroll
      for (int n = 24; n < 32; ++n) {
        s16x8 vz = *(const s16x8*)(wlz + n*32);
        s16x8 vr = *(const s16x8*)(wlr + n*32);
        acz = __builtin_amdgcn_mfma_f32_16x16x32_bf16(ah[n], vz, acz, 0,0,0);
        acr = __builtin_amdgcn_mfma_f32_16x16x32_bf16(ah[n], vr, acr, 0,0,0);
      }
      #pragma unroll
      for (int i = 0; i < 4; ++i) {
        zreg[i] = sigm(bf2f(xs[i]) + acz[i] + bz);
        float r = sigm(bf2f(xs[4+i]) + acr[i] + br);
        __hip_atomic_store(rh + (b0+i)*1024 + j, f2bf(r * hreg[i]),
                           __ATOMIC_RELAXED, __HIP_MEMORY_SCOPE_AGENT);
      }
    }
    { // barrier (domain bg)
      asm volatile("s_waitcnt vmcnt(0)" ::: "memory");
      if (lane == 0)
        __hip_atomic_store(fslot, seq, __ATOMIC_RELAXED, __HIP_MEMORY_SCOPE_AGENT);
      int fl;
      do { fl = __hip_atomic_load(fpoll, __ATOMIC_RELAXED, __HIP_MEMORY_SCOPE_AGENT); }
      while (!__all(fl >= seq));
      ++seq;
    }

    { // ---- phase 2: h_hat, combine ----
      const short* ap = rh + (size_t)arow*1024 + kfo;
      s16x8 ah[32];
      cload8(ap,     ah[0], ah[1], ah[2], ah[3], ah[4], ah[5], ah[6], ah[7]);
      cload8(ap+256, ah[8], ah[9], ah[10],ah[11],ah[12],ah[13],ah[14],ah[15]);
      cload8(ap+512, ah[16],ah[17],ah[18],ah[19],ah[20],ah[21],ah[22],ah[23]);
      cload8(ap+768, ah[24],ah[25],ah[26],ah[27],ah[28],ah[29],ah[30],ah[31]);
      f32x4 ach = {0.f,0.f,0.f,0.f};
      WAITV(24)
      #pragma unroll
      for (int n = 0; n < 8; ++n) {
        s16x8 vh = *(const s16x8*)(wlh + n*32);
        ach = __builtin_amdgcn_mfma_f32_16x16x32_bf16(ah[n], vh, ach, 0,0,0);
      }
      WAITV(16)
      #pragma unroll
      for (int n = 8; n < 16; ++n) {
        s16x8 vh = *(const s16x8*)(wlh + n*32);
        ach = __builtin_amdgcn_mfma_f32_16x16x32_bf16(ah[n], vh, ach, 0,0,0);
      }
      WAITV(8)
      #pragma unroll
      for (int n = 16; n < 24; ++n) {
        s16x8 vh = *(const s16x8*)(wlh + n*32);
        ach = __builtin_amdgcn_mfma_f32_16x16x32_bf16(ah[n], vh, ach, 0,0,0);
      }
      WAITV(0)
      #pragma unroll
      for (int n = 24; n < 32; ++n) {
        s16x8 vh = *(const s16x8*)(wlh + n*32);
        ach = __builtin_amdgcn_mfma_f32_16x16x32_bf16(ah[n], vh, ach, 0,0,0);
      }
      #pragma unroll
      for (int i = 0; i < 4; ++i) {
        float s  = bf2f(xs[8+i]) + ach[i] + bh;
        float hh = s * sigm(s);
        float hn = (1.0f - zreg[i])*hreg[i] + zreg[i]*hh;
        hreg[i] = hn;
        __builtin_nontemporal_store(hn, y + ((size_t)(b0+i)*512 + t)*1024 + j);
        __hip_atomic_store(hbn + (b0+i)*1024 + j, f2bf(hn),
                           __ATOMIC_RELAXED, __HIP_MEMORY_SCOPE_AGENT);
      }
      if (t == 511) {
        #pragma unroll
        for (int i = 0; i < 4; ++i) hlast[(b0+i)*1024 + j] = hreg[i];
      }
    }
    { // barrier (domain bg)
      asm volatile("s_waitcnt vmcnt(0)" ::: "memory");
      if (lane == 0)
        __hip_atomic_store(fslot, seq, __ATOMIC_RELAXED, __HIP_MEMORY_SCOPE_AGENT);
      int fl;
      do { fl = __hip_atomic_load(fpoll, __ATOMIC_RELAXED, __HIP_MEMORY_SCOPE_AGENT); }
      while (!__all(fl >= seq));
      ++seq;
    }

    #pragma unroll
    for (int q = 0; q < 12; ++q) xs[q] = xn[q];
  }
}

extern "C" void kernel_launch(void* const* d_in, const int* in_sizes, int n_in,
                              void* d_out, int out_size, void* d_ws, size_t ws_size,
                              hipStream_t stream) {
  const float* x   = (const float*)d_in[0];
  const float* h0  = (const float*)d_in[1];
  const float* Wfz = (const float*)d_in[2];
  const float* bfz = (const float*)d_in[3];
  const float* Wfr = (const float*)d_in[4];
  const float* bfr = (const float*)d_in[5];
  const float* Wfh = (const float*)d_in[6];
  const float* bfh = (const float*)d_in[7];
  const float* Wuz = (const float*)d_in[8];
  const float* buz = (const float*)d_in[9];
  const float* Wur = (const float*)d_in[10];
  const float* bur = (const float*)d_in[11];
  const float* Wuh = (const float*)d_in[12];
  const float* buh = (const float*)d_in[13];

  char* ws = (char*)d_ws;
  short* Xb  = (short*)(ws);                  // 201326592 B  [512][64][3072] bf16
  short* xb  = (short*)(ws + 201326592);      //  67108864 B
  short* Wf  = (short*)(ws + 268435456);      //   6291456 B
  short* Wzr = (short*)(ws + 274726912);      //   4194304 B
  short* Wh  = (short*)(ws + 278921216);      //   2097152 B
  short* hb  = (short*)(ws + 281018368);      //    262144 B
  short* rh  = (short*)(ws + 281280512);      //    131072 B
  int*   bar = (int*)(ws + 281411584);        //     32768 B flags[256*32]

  float* y = (float*)d_out;
  float* hlast = y + 33554432;

  hipMemsetAsync(bar, 0, 32768, stream);
  prep<<<2048, 256, 0, stream>>>(x, Wfz, Wfr, Wfh, Wuz, Wur, Wuh, h0, xb, Wf, Wzr, Wh, hb);
  gemm_x<<<6144, 256, 0, stream>>>(xb, Wf, bfz, bfr, bfh, Xb);
  recur<<<256, 64, 0, stream>>>(Xb, Wzr, Wh, h0, buz, bur, buh, hb, rh, y, hlast, bar);
}